// Round 3
// baseline (505.860 us; speedup 1.0000x reference)
//
#include <hip/hip_runtime.h>
#include <hip/hip_bf16.h>
#include <stdint.h>
#include <stddef.h>

#define D_M   1024
#define N_H   16
#define D_K   64
#define S_LEN 2048
#define N_B   4
#define P_LEN 1792
#define M_ROWS (N_B*S_LEN)   // 8192

// 0.125 * log2(e): folds 1/sqrt(dk) and the exp->exp2 conversion into Q
#define QSCALE 0.1803368801111601f

typedef unsigned short u16;
typedef __bf16  bf16x8 __attribute__((ext_vector_type(8)));
typedef __bf16  bf16x4 __attribute__((ext_vector_type(4)));
typedef short   s16x4  __attribute__((ext_vector_type(4)));
typedef float   f32x4  __attribute__((ext_vector_type(4)));

#define MFMA32(a,b,c) __builtin_amdgcn_mfma_f32_16x16x32_bf16((a),(b),(c),0,0,0)

// 16x16x16 bf16 MFMA. Host pass gets an inert stub (never executed); device
// pass tries the two builtin spellings, then falls back to raw asm (the
// instruction v_mfma_f32_16x16x16_bf16 exists on gfx950 per the ISA table).
__device__ __forceinline__ f32x4 mfma16k(bf16x4 a, bf16x4 b, f32x4 c){
#if !defined(__HIP_DEVICE_COMPILE__)
  (void)a; (void)b; return c;
#elif __has_builtin(__builtin_amdgcn_mfma_f32_16x16x16_bf16)
  return __builtin_amdgcn_mfma_f32_16x16x16_bf16(a, b, c, 0, 0, 0);
#elif __has_builtin(__builtin_amdgcn_mfma_f32_16x16x16bf16_1k)
  return __builtin_amdgcn_mfma_f32_16x16x16bf16_1k(
      __builtin_bit_cast(s16x4, a), __builtin_bit_cast(s16x4, b), c, 0, 0, 0);
#else
  f32x4 d;
  asm("v_mfma_f32_16x16x16_bf16 %0, %1, %2, %3"
      : "=v"(d) : "v"(a), "v"(b), "v"(c));
  return d;
#endif
}

__device__ __forceinline__ float ex2(float x){
#if defined(__HIP_DEVICE_COMPILE__) && __has_builtin(__builtin_amdgcn_exp2f)
  return __builtin_amdgcn_exp2f(x);
#else
  return exp2f(x);
#endif
}

#define GLDS16(gp, lp) __builtin_amdgcn_global_load_lds( \
    (__attribute__((address_space(1))) void*)(gp), \
    (__attribute__((address_space(3))) void*)(lp), 16, 0, 0)

__device__ __forceinline__ u16 f2bf(float f){
  unsigned u = __builtin_bit_cast(unsigned, f);
  u += 0x7FFFu + ((u>>16)&1u);     // RNE round to bf16
  return (u16)(u>>16);
}

__device__ __forceinline__ bf16x4 pack4(f32x4 v){
  bf16x4 o;
  o[0]=(__bf16)v[0]; o[1]=(__bf16)v[1]; o[2]=(__bf16)v[2]; o[3]=(__bf16)v[3];
  return o;   // compiler emits v_cvt_pk_bf16_f32 pairs
}

// ---------------- fp32 -> bf16 convert (vectorized, 8 elems/thread/iter) ----
__global__ void cvt_bf16(const float* __restrict__ in, u16* __restrict__ out, int n8){
  typedef u16 u16x8 __attribute__((ext_vector_type(8)));
  for (int i = blockIdx.x*blockDim.x + threadIdx.x; i < n8; i += gridDim.x*blockDim.x){
    const float4* p = (const float4*)(in + (size_t)i*8);
    float4 a = p[0], b = p[1];
    u16x8 o;
    o[0]=f2bf(a.x); o[1]=f2bf(a.y); o[2]=f2bf(a.z); o[3]=f2bf(a.w);
    o[4]=f2bf(b.x); o[5]=f2bf(b.y); o[6]=f2bf(b.z); o[7]=f2bf(b.w);
    *(u16x8*)(out + (size_t)i*8) = o;
  }
}

// ---------------- 128x128 bf16 NT GEMM (C = (A*B^T + bias)*scale), m97 ------
// MODE 0: out bf16 (B,H,S,dk) head-split       (Q / K projections)
// MODE 1: out bf16 (B,H,dk,S) head-split, transposed   (V projection)
// MODE 2: out fp32 (M,N) row-major             (output projection -> d_out)
template<int MODE>
__global__ __launch_bounds__(256,2)
void gemm_bt(const u16* __restrict__ A, const u16* __restrict__ Bm,
             const float* __restrict__ bias, void* __restrict__ Cout, float scale)
{
  constexpr int Kd = 1024, N = 1024;
  __shared__ __align__(16) u16 As[128*32];
  __shared__ __align__(16) u16 Bs[128*32];
  const int tid  = threadIdx.x;
  const int wid  = tid >> 6, lane = tid & 63;
  const int rowBase = blockIdx.x * 128, colBase = blockIdx.y * 128;

  const int srow = (wid<<4) + (lane>>2);
  const int scol = (lane&3) << 3;
  const u16* Ag0 = A  + (size_t)(rowBase + srow)*Kd + scol;
  const u16* Ag1 = Ag0 + (size_t)64*Kd;
  const u16* Bg0 = Bm + (size_t)(colBase + srow)*Kd + scol;
  const u16* Bg1 = Bg0 + (size_t)64*Kd;
  u16* AsW0 = As + (wid<<9);
  u16* AsW1 = As + 2048 + (wid<<9);
  u16* BsW0 = Bs + (wid<<9);
  u16* BsW1 = Bs + 2048 + (wid<<9);

  f32x4 acc[4][4] = {};
  const int fr = lane & 15, fk = (lane>>4) << 3;
  const int wr = (wid>>1) << 6, wc = (wid&1) << 6;

  for (int kt = 0; kt < Kd/32; ++kt){
    __syncthreads();
    const int ko = kt*32;
    GLDS16(Ag0+ko, AsW0); GLDS16(Ag1+ko, AsW1);
    GLDS16(Bg0+ko, BsW0); GLDS16(Bg1+ko, BsW1);
    __syncthreads();
    bf16x8 af[4], bf[4];
#pragma unroll
    for (int i=0;i<4;++i) af[i] = *(const bf16x8*)&As[(wr + i*16 + fr)*32 + fk];
#pragma unroll
    for (int i=0;i<4;++i) bf[i] = *(const bf16x8*)&Bs[(wc + i*16 + fr)*32 + fk];
#pragma unroll
    for (int i=0;i<4;++i)
#pragma unroll
      for (int j=0;j<4;++j)
        acc[i][j] = MFMA32(af[i], bf[j], acc[i][j]);
  }

  const int rr0 = (lane>>4) << 2;
#pragma unroll
  for (int i=0;i<4;++i){
#pragma unroll
    for (int j=0;j<4;++j){
      const int gc = colBase + wc + j*16 + fr;
      const float bb = bias[gc];
#pragma unroll
      for (int r=0;r<4;++r){
        const int gr = rowBase + wr + i*16 + rr0 + r;
        const float v = (acc[i][j][r] + bb) * scale;
        if (MODE == 2){
          ((float*)Cout)[(size_t)gr*N + gc] = v;
        } else {
          const int b = gr >> 11, s = gr & 2047;
          const int h = gc >> 6,  k = gc & 63;
          if (MODE == 0)
            ((u16*)Cout)[(((size_t)(b*N_H + h))*S_LEN + s)*D_K + k] = f2bf(v);
          else
            ((u16*)Cout)[(((size_t)(b*N_H + h))*D_K + k)*S_LEN + s] = f2bf(v);
        }
      }
    }
  }
}

// ---------------- attention tile (swapped QK^T, lane-local softmax) ----------
// Lane layout: q = lane&15 (one q-row per lane), g = lane>>4.
// QK output (swapped): s[t][r] = S2[k = kv+16t+4g+r][q], already log2-domain.
// PV: mfma 16x16x16 with A = V^T frag, B = s (exact layout match, no remap).
// NT: #16-key blocks (1 or 2). MM: 0 none, 1 causal (k>q), 2 diag-only (k==q).
template<int NT, int MM>
__device__ __forceinline__ void attn_tile(
  const u16* __restrict__ Kb, const u16* __restrict__ Vb,
  bf16x8 qf0, bf16x8 qf1, int kv, int qg,
  int fr, int g, float& m, float& l, f32x4* oacc)
{
  const int fk = g << 3;
  f32x4 s[NT];
#pragma unroll
  for (int t=0;t<NT;++t){
    const u16* kp = Kb + (size_t)(kv + 16*t + fr) * D_K;
    bf16x8 k0 = *(const bf16x8*)(kp + fk);
    bf16x8 k1 = *(const bf16x8*)(kp + 32 + fk);
    f32x4 z = {0.f,0.f,0.f,0.f};
    z = MFMA32(k0, qf0, z);
    z = MFMA32(k1, qf1, z);
    s[t] = z;
  }
#pragma unroll
  for (int t=0;t<NT;++t){
#pragma unroll
    for (int r=0;r<4;++r){
      const int k = kv + 16*t + 4*g + r;
      if (MM == 1){ if (k > qg)        s[t][r] = -1e30f; }
      if (MM == 2){ if (4*g + r != fr) s[t][r] = -1e30f; }
    }
  }
  // tile max for this q: in-lane + 2 butterfly rounds (lanes sharing lane&15)
  float tm = s[0][0];
#pragma unroll
  for (int t=0;t<NT;++t)
#pragma unroll
    for (int r=0;r<4;++r) tm = fmaxf(tm, s[t][r]);
  tm = fmaxf(tm, __shfl_xor(tm, 16, 64));
  tm = fmaxf(tm, __shfl_xor(tm, 32, 64));

  const bool skip = __all(tm <= m);     // defer rescale when max didn't grow
  float mn = m, alpha = 1.f;
  if (!skip){ mn = fmaxf(m, tm); alpha = ex2(m - mn); m = mn; }

  float rs = 0.f;
  f32x4 p[NT];
#pragma unroll
  for (int t=0;t<NT;++t)
#pragma unroll
    for (int r=0;r<4;++r){ float pv = ex2(s[t][r] - mn); p[t][r] = pv; rs += pv; }
  rs += __shfl_xor(rs, 16, 64);
  rs += __shfl_xor(rs, 32, 64);

  bf16x4 pf[NT];
#pragma unroll
  for (int t=0;t<NT;++t) pf[t] = pack4(p[t]);

  if (!skip){
    l = l*alpha + rs;
#pragma unroll
    for (int dt=0;dt<4;++dt) oacc[dt] *= alpha;
  } else {
    l += rs;
  }

#pragma unroll
  for (int dt=0;dt<4;++dt){
    const u16* vp = Vb + (size_t)(dt*16 + fr)*S_LEN + kv + 4*g;
#pragma unroll
    for (int t=0;t<NT;++t){
      bf16x4 vf = *(const bf16x4*)(vp + 16*t);
      oacc[dt] = mfma16k(vf, pf[t], oacc[dt]);   // O^T[d][q] accumulate
    }
  }
}

__device__ __forceinline__ void attn_write(
  u16* __restrict__ ctx, int bh, int qg, int fr, int g, float l, const f32x4* oacc)
{
  const int b = bh >> 4, h = bh & 15;
  const float inv = 1.f / l;
  u16* cp = ctx + ((size_t)b*S_LEN + qg)*D_M + h*D_K + 4*g;
#pragma unroll
  for (int dt=0;dt<4;++dt){
    f32x4 o = oacc[dt] * inv;          // lane holds d = dt*16+4g+r, q = lane&15
    *(bf16x4*)(cp + dt*16) = pack4(o);
  }
}

// ---------------- prefix causal attention: rows [0,P) ------------------------
__global__ __launch_bounds__(256)
void attn_prefix(const u16* __restrict__ Q, const u16* __restrict__ K,
                 const u16* __restrict__ Vt, u16* __restrict__ ctx)
{
  const int bh = blockIdx.x;
  const int qt = gridDim.y - 1 - blockIdx.y;       // heavy blocks first (LPT)
  const int wid = threadIdx.x >> 6, lane = threadIdx.x & 63;
  const int fr = lane & 15, g = lane >> 4, fk = g << 3;
  const int qb = qt*64 + wid*16;
  const int qg = qb + fr;
  const u16* Kb = K  + (size_t)bh * S_LEN * D_K;
  const u16* Vb = Vt + (size_t)bh * D_K * S_LEN;
  const u16* Qp = Q + ((size_t)bh * S_LEN + qg) * D_K;
  bf16x8 qf0 = *(const bf16x8*)(Qp + fk);
  bf16x8 qf1 = *(const bf16x8*)(Qp + 32 + fk);
  float m = -1e30f, l = 0.f;
  f32x4 oacc[4] = {};

  const int nfull = qb >> 5;            // tiles with kv+31 <= qb: no mask needed
  int kv = 0;
  for (int i=0;i<nfull;++i, kv+=32)
    attn_tile<2,0>(Kb, Vb, qf0, qf1, kv, qg, fr, g, m, l, oacc);
  attn_tile<2,1>(Kb, Vb, qf0, qf1, kv, qg, fr, g, m, l, oacc);  // diagonal tile

  attn_write(ctx, bh, qg, fr, g, l, oacc);
}

// ---------------- candidate attention: rows [P,S), keys = prefix + self ------
__global__ __launch_bounds__(256)
void attn_cand(const u16* __restrict__ Q, const u16* __restrict__ K,
               const u16* __restrict__ Vt, u16* __restrict__ ctx)
{
  const int bh = blockIdx.x, qt = blockIdx.y;      // qt in [0,4)
  const int wid = threadIdx.x >> 6, lane = threadIdx.x & 63;
  const int fr = lane & 15, g = lane >> 4, fk = g << 3;
  const int ql = qt*64 + wid*16;                   // local candidate base [0,256)
  const int qg = P_LEN + ql + fr;
  const u16* Kb = K  + (size_t)bh * S_LEN * D_K;
  const u16* Vb = Vt + (size_t)bh * D_K * S_LEN;
  const u16* Qp = Q + ((size_t)bh * S_LEN + qg) * D_K;
  bf16x8 qf0 = *(const bf16x8*)(Qp + fk);
  bf16x8 qf1 = *(const bf16x8*)(Qp + 32 + fk);
  float m = -1e30f, l = 0.f;
  f32x4 oacc[4] = {};

  for (int kv = 0; kv < P_LEN; kv += 32)           // all prefix keys, no mask
    attn_tile<2,0>(Kb, Vb, qf0, qf1, kv, qg, fr, g, m, l, oacc);
  attn_tile<1,2>(Kb, Vb, qf0, qf1, P_LEN + ql, qg, fr, g, m, l, oacc); // self

  attn_write(ctx, bh, qg, fr, g, l, oacc);
}

// ---------------- launcher ---------------------------------------------------
extern "C" void kernel_launch(void* const* d_in, const int* in_sizes, int n_in,
                              void* d_out, int out_size, void* d_ws, size_t ws_size,
                              hipStream_t stream)
{
  const float* query = (const float*)d_in[0];
  const float* key   = (const float*)d_in[1];
  const float* value = (const float*)d_in[2];
  const float* Wq = (const float*)d_in[3];
  const float* bq = (const float*)d_in[4];
  const float* Wk = (const float*)d_in[5];
  const float* bk = (const float*)d_in[6];
  const float* Wv = (const float*)d_in[7];
  const float* bv = (const float*)d_in[8];
  const float* Wo = (const float*)d_in[9];
  const float* bo = (const float*)d_in[10];

  if (ws_size < (size_t)(66u<<20)) return;

  char* ws = (char*)d_ws;
  u16* Xb = (u16*)(ws);                          // 16 MiB: bf16 input (reused x3), then ctx
  u16* Wb = (u16*)(ws + (16u<<20));              //  2 MiB: bf16 weight (reused x4)
  u16* Qb = (u16*)(ws + (18u<<20));              // 16 MiB: Q (B,H,S,dk), pre-scaled
  u16* Kb = (u16*)(ws + (34u<<20));              // 16 MiB: K (B,H,S,dk)
  u16* Vb = (u16*)(ws + (50u<<20));              // 16 MiB: V^T (B,H,dk,S)
  u16* ctx = Xb;

  const int nX8 = (M_ROWS*D_M)/8, nW8 = (D_M*D_M)/8;
  dim3 gg(M_ROWS/128, D_M/128);

  cvt_bf16<<<2048,256,0,stream>>>(query, Xb, nX8);
  cvt_bf16<<<512, 256,0,stream>>>(Wq,    Wb, nW8);
  gemm_bt<0><<<gg,256,0,stream>>>(Xb, Wb, bq, Qb, QSCALE);

  cvt_bf16<<<2048,256,0,stream>>>(key,   Xb, nX8);
  cvt_bf16<<<512, 256,0,stream>>>(Wk,    Wb, nW8);
  gemm_bt<0><<<gg,256,0,stream>>>(Xb, Wb, bk, Kb, 1.0f);

  cvt_bf16<<<2048,256,0,stream>>>(value, Xb, nX8);
  cvt_bf16<<<512, 256,0,stream>>>(Wv,    Wb, nW8);
  gemm_bt<1><<<gg,256,0,stream>>>(Xb, Wb, bv, Vb, 1.0f);

  attn_prefix<<<dim3(N_H*N_B, P_LEN/64),256,0,stream>>>(Qb, Kb, Vb, ctx);
  attn_cand  <<<dim3(N_H*N_B, (S_LEN-P_LEN)/64),256,0,stream>>>(Qb, Kb, Vb, ctx);

  cvt_bf16<<<512,256,0,stream>>>(Wo, Wb, nW8);
  gemm_bt<2><<<gg,256,0,stream>>>(ctx, Wb, bo, (float*)d_out, 1.0f);
}

// Round 4
// 333.688 us; speedup vs baseline: 1.5160x; 1.5160x over previous
//
#include <hip/hip_runtime.h>
#include <hip/hip_bf16.h>
#include <stdint.h>
#include <stddef.h>

#define D_M   1024
#define N_H   16
#define D_K   64
#define S_LEN 2048
#define N_B   4
#define P_LEN 1792
#define M_ROWS (N_B*S_LEN)   // 8192

// 0.125 * log2(e): folds 1/sqrt(dk) and the exp->exp2 conversion into Q
#define QSCALE 0.1803368801111601f

typedef unsigned short u16;
typedef __bf16  bf16x8 __attribute__((ext_vector_type(8)));
typedef __bf16  bf16x4 __attribute__((ext_vector_type(4)));
typedef __bf16  bf16x2 __attribute__((ext_vector_type(2)));
typedef float   f32x4  __attribute__((ext_vector_type(4)));
typedef float   f32x16 __attribute__((ext_vector_type(16)));
typedef unsigned u32x4 __attribute__((ext_vector_type(4)));

#define MFMA32(a,b,c)   __builtin_amdgcn_mfma_f32_16x16x32_bf16((a),(b),(c),0,0,0)
#define MFMA3216(a,b,c) __builtin_amdgcn_mfma_f32_32x32x16_bf16((a),(b),(c),0,0,0)

__device__ __forceinline__ float ex2(float x){
#if defined(__HIP_DEVICE_COMPILE__) && __has_builtin(__builtin_amdgcn_exp2f)
  return __builtin_amdgcn_exp2f(x);
#else
  return exp2f(x);
#endif
}

#define GLDS16(gp, lp) __builtin_amdgcn_global_load_lds( \
    (__attribute__((address_space(1))) void*)(gp), \
    (__attribute__((address_space(3))) void*)(lp), 16, 0, 0)

__device__ __forceinline__ u16 f2bf(float f){
  unsigned u = __builtin_bit_cast(unsigned, f);
  u += 0x7FFFu + ((u>>16)&1u);     // RNE round to bf16
  return (u16)(u>>16);
}

__device__ __forceinline__ unsigned pkbf(float a, float b){
  bf16x2 t; t[0] = (__bf16)a; t[1] = (__bf16)b;
  return __builtin_bit_cast(unsigned, t);   // compiler emits v_cvt_pk_bf16_f32
}

// v_permlane32_swap_b32: swaps the high 32 lanes of x with the low 32 lanes
// of y. After: x = [x_lo | y_lo_old], y = [x_hi_old | y_hi].  (gfx950)
__device__ __forceinline__ void plswap(unsigned &x, unsigned &y){
  asm("v_permlane32_swap_b32 %0, %1" : "+v"(x), "+v"(y));
}

// ---------------- fp32 -> bf16 convert (vectorized, 8 elems/thread/iter) ----
__global__ void cvt_bf16(const float* __restrict__ in, u16* __restrict__ out, int n8){
  typedef u16 u16x8 __attribute__((ext_vector_type(8)));
  for (int i = blockIdx.x*blockDim.x + threadIdx.x; i < n8; i += gridDim.x*blockDim.x){
    const float4* p = (const float4*)(in + (size_t)i*8);
    float4 a = p[0], b = p[1];
    u16x8 o;
    o[0]=f2bf(a.x); o[1]=f2bf(a.y); o[2]=f2bf(a.z); o[3]=f2bf(a.w);
    o[4]=f2bf(b.x); o[5]=f2bf(b.y); o[6]=f2bf(b.z); o[7]=f2bf(b.w);
    *(u16x8*)(out + (size_t)i*8) = o;
  }
}

// ---------------- 128x128 bf16 NT GEMM (C = (A*B^T + bias)*scale), m97 ------
// MODE 0: out bf16 (B,H,S,dk) head-split       (Q / K projections)
// MODE 1: out bf16 (B,H,dk,S) head-split, transposed   (V projection)
// MODE 2: out fp32 (M,N) row-major             (output projection -> d_out)
template<int MODE>
__global__ __launch_bounds__(256,2)
void gemm_bt(const u16* __restrict__ A, const u16* __restrict__ Bm,
             const float* __restrict__ bias, void* __restrict__ Cout, float scale)
{
  constexpr int Kd = 1024, N = 1024;
  __shared__ __align__(16) u16 As[128*32];
  __shared__ __align__(16) u16 Bs[128*32];
  const int tid  = threadIdx.x;
  const int wid  = tid >> 6, lane = tid & 63;
  const int rowBase = blockIdx.x * 128, colBase = blockIdx.y * 128;

  const int srow = (wid<<4) + (lane>>2);
  const int scol = (lane&3) << 3;
  const u16* Ag0 = A  + (size_t)(rowBase + srow)*Kd + scol;
  const u16* Ag1 = Ag0 + (size_t)64*Kd;
  const u16* Bg0 = Bm + (size_t)(colBase + srow)*Kd + scol;
  const u16* Bg1 = Bg0 + (size_t)64*Kd;
  u16* AsW0 = As + (wid<<9);
  u16* AsW1 = As + 2048 + (wid<<9);
  u16* BsW0 = Bs + (wid<<9);
  u16* BsW1 = Bs + 2048 + (wid<<9);

  f32x4 acc[4][4] = {};
  const int fr = lane & 15, fk = (lane>>4) << 3;
  const int wr = (wid>>1) << 6, wc = (wid&1) << 6;

  for (int kt = 0; kt < Kd/32; ++kt){
    __syncthreads();
    const int ko = kt*32;
    GLDS16(Ag0+ko, AsW0); GLDS16(Ag1+ko, AsW1);
    GLDS16(Bg0+ko, BsW0); GLDS16(Bg1+ko, BsW1);
    __syncthreads();
    bf16x8 af[4], bf[4];
#pragma unroll
    for (int i=0;i<4;++i) af[i] = *(const bf16x8*)&As[(wr + i*16 + fr)*32 + fk];
#pragma unroll
    for (int i=0;i<4;++i) bf[i] = *(const bf16x8*)&Bs[(wc + i*16 + fr)*32 + fk];
#pragma unroll
    for (int i=0;i<4;++i)
#pragma unroll
      for (int j=0;j<4;++j)
        acc[i][j] = MFMA32(af[i], bf[j], acc[i][j]);
  }

  const int rr0 = (lane>>4) << 2;
#pragma unroll
  for (int i=0;i<4;++i){
#pragma unroll
    for (int j=0;j<4;++j){
      const int gc = colBase + wc + j*16 + fr;
      const float bb = bias[gc];
#pragma unroll
      for (int r=0;r<4;++r){
        const int gr = rowBase + wr + i*16 + rr0 + r;
        const float v = (acc[i][j][r] + bb) * scale;
        if (MODE == 2){
          ((float*)Cout)[(size_t)gr*N + gc] = v;
        } else {
          const int b = gr >> 11, s = gr & 2047;
          const int h = gc >> 6,  k = gc & 63;
          if (MODE == 0)
            ((u16*)Cout)[(((size_t)(b*N_H + h))*S_LEN + s)*D_K + k] = f2bf(v);
          else
            ((u16*)Cout)[(((size_t)(b*N_H + h))*D_K + k)*S_LEN + s] = f2bf(v);
        }
      }
    }
  }
}

// ---------------- attention 32x32 tile (swapped QK^T, 32x32x16 MFMA) ---------
// Lane: q-col = lane&31, half h = lane>>5.
// QK (swapped, A=K rows, B=Q cols): S^T[k][q]; lane holds 16 k-rows:
//   k = ksub + (reg&3) + 8*(reg>>2) + 4h   (log2-domain scores, QSCALE folded)
// Softmax lane-local + one shfl_xor(32).
// P^T -> PV B-frag (k = 16kb + 8h + j): 8 cvt_pk + 4 permlane32_swap (T12).
// PV: A = V^T (d rows), B = P^T -> O^T[d][q] in 2x f32x16.
// MM: 0 none, 1 causal (k>qg), 2 diag-only (krow==q).
template<int MM>
__device__ __forceinline__ void attn_tile32(
  const u16* __restrict__ Kb, const u16* __restrict__ Vb,
  const bf16x8* qf, int ksub, int qg, int h, int q,
  float& m, float& l, f32x16* oacc)
{
  const u16* kp = Kb + (size_t)(ksub + q) * D_K + (h<<3);  // A-frag row = lane&31
  f32x16 s = {};
#pragma unroll
  for (int kb=0;kb<4;++kb){
    bf16x8 kf = *(const bf16x8*)(kp + 16*kb);
    s = MFMA3216(kf, qf[kb], s);
  }

  if (MM != 0){
#pragma unroll
    for (int r=0;r<16;++r){
      const int krow = (r&3) + 8*(r>>2) + 4*h;
      if (MM == 1){ if (ksub + krow > qg) s[r] = -1e30f; }
      if (MM == 2){ if (krow != q)        s[r] = -1e30f; }
    }
  }

  float tm = s[0];
#pragma unroll
  for (int r=1;r<16;++r) tm = fmaxf(tm, s[r]);
  tm = fmaxf(tm, __shfl_xor(tm, 32, 64));

  const bool skip = __all(tm <= m);     // defer rescale when max didn't grow
  float mn = m;
  if (!skip) mn = fmaxf(m, tm);

  float rs = 0.f;
#pragma unroll
  for (int r=0;r<16;++r){ float pv = ex2(s[r] - mn); s[r] = pv; rs += pv; }
  rs += __shfl_xor(rs, 32, 64);

  if (!skip){
    const float alpha = ex2(m - mn);
    m = mn;
    l = l*alpha + rs;
#pragma unroll
    for (int r=0;r<16;++r){ oacc[0][r] *= alpha; oacc[1][r] *= alpha; }
  } else {
    l += rs;
  }

  unsigned w[8];
#pragma unroll
  for (int i=0;i<8;++i) w[i] = pkbf(s[2*i], s[2*i+1]);
  plswap(w[0], w[2]); plswap(w[1], w[3]);   // k-block 0
  plswap(w[4], w[6]); plswap(w[5], w[7]);   // k-block 1
  bf16x8 pf0 = __builtin_bit_cast(bf16x8, (u32x4){w[0],w[1],w[2],w[3]});
  bf16x8 pf1 = __builtin_bit_cast(bf16x8, (u32x4){w[4],w[5],w[6],w[7]});

  const u16* vp = Vb + (size_t)q * S_LEN + ksub + (h<<3);  // V^T row = 32db + q
#pragma unroll
  for (int db=0;db<2;++db){
    const u16* vpd = vp + (size_t)(32*db) * S_LEN;
    bf16x8 v0 = *(const bf16x8*)(vpd);        // k = ksub +  0 + 8h + j
    bf16x8 v1 = *(const bf16x8*)(vpd + 16);   // k = ksub + 16 + 8h + j
    oacc[db] = MFMA3216(v0, pf0, oacc[db]);
    oacc[db] = MFMA3216(v1, pf1, oacc[db]);
  }
}

__device__ __forceinline__ void attn_write32(
  u16* __restrict__ ctx, int bh, int qg, int h, float l, const f32x16* oacc)
{
  const int b = bh >> 4, hd = bh & 15;
  const float inv = 1.f / l;
  u16* cp = ctx + ((size_t)b*S_LEN + qg)*D_M + hd*D_K;
#pragma unroll
  for (int db=0;db<2;++db){
#pragma unroll
    for (int rg=0;rg<4;++rg){
      const int d0 = 32*db + 8*rg + 4*h;     // O^T row = (reg&3)+8*(reg>>2)+4h
      bf16x4 o;
#pragma unroll
      for (int e=0;e<4;++e) o[e] = (__bf16)(oacc[db][4*rg+e] * inv);
      *(bf16x4*)(cp + d0) = o;
    }
  }
}

// ---------------- prefix causal attention: rows [0,P) ------------------------
__global__ __launch_bounds__(256)
void attn_prefix(const u16* __restrict__ Q, const u16* __restrict__ K,
                 const u16* __restrict__ Vt, u16* __restrict__ ctx)
{
  const int bh = blockIdx.x;
  const int qt = gridDim.y - 1 - blockIdx.y;       // heavy blocks first (LPT)
  const int wid = threadIdx.x >> 6, lane = threadIdx.x & 63;
  const int q = lane & 31, h = lane >> 5;
  const int qbase = qt*128 + wid*32;
  const int qg = qbase + q;
  const u16* Kb = K  + (size_t)bh * S_LEN * D_K;
  const u16* Vb = Vt + (size_t)bh * D_K * S_LEN;
  const u16* Qp = Q + ((size_t)bh * S_LEN + qg) * D_K + (h<<3);
  bf16x8 qf[4];
#pragma unroll
  for (int kb=0;kb<4;++kb) qf[kb] = *(const bf16x8*)(Qp + 16*kb);
  float m = -1e30f, l = 0.f;
  f32x16 oacc[2] = {};

  const int nfull = qbase >> 5;       // unmasked tiles: keys < qbase
  int ks = 0;
  for (int i=0;i<nfull;++i, ks+=32)
    attn_tile32<0>(Kb, Vb, qf, ks, qg, h, q, m, l, oacc);
  attn_tile32<1>(Kb, Vb, qf, ks, qg, h, q, m, l, oacc);   // diagonal tile

  attn_write32(ctx, bh, qg, h, l, oacc);
}

// ---------------- candidate attention: rows [P,S), keys = prefix + self ------
__global__ __launch_bounds__(256)
void attn_cand(const u16* __restrict__ Q, const u16* __restrict__ K,
               const u16* __restrict__ Vt, u16* __restrict__ ctx)
{
  const int bh = blockIdx.x, qt = blockIdx.y;      // qt in [0,2)
  const int wid = threadIdx.x >> 6, lane = threadIdx.x & 63;
  const int q = lane & 31, h = lane >> 5;
  const int ql = qt*128 + wid*32;                  // local candidate base [0,256)
  const int qg = P_LEN + ql + q;
  const u16* Kb = K  + (size_t)bh * S_LEN * D_K;
  const u16* Vb = Vt + (size_t)bh * D_K * S_LEN;
  const u16* Qp = Q + ((size_t)bh * S_LEN + qg) * D_K + (h<<3);
  bf16x8 qf[4];
#pragma unroll
  for (int kb=0;kb<4;++kb) qf[kb] = *(const bf16x8*)(Qp + 16*kb);
  float m = -1e30f, l = 0.f;
  f32x16 oacc[2] = {};

  for (int ks = 0; ks < P_LEN; ks += 32)           // all prefix keys, no mask
    attn_tile32<0>(Kb, Vb, qf, ks, qg, h, q, m, l, oacc);
  attn_tile32<2>(Kb, Vb, qf, P_LEN + ql, qg, h, q, m, l, oacc); // self (diag)

  attn_write32(ctx, bh, qg, h, l, oacc);
}

// ---------------- launcher ---------------------------------------------------
extern "C" void kernel_launch(void* const* d_in, const int* in_sizes, int n_in,
                              void* d_out, int out_size, void* d_ws, size_t ws_size,
                              hipStream_t stream)
{
  const float* query = (const float*)d_in[0];
  const float* key   = (const float*)d_in[1];
  const float* value = (const float*)d_in[2];
  const float* Wq = (const float*)d_in[3];
  const float* bq = (const float*)d_in[4];
  const float* Wk = (const float*)d_in[5];
  const float* bk = (const float*)d_in[6];
  const float* Wv = (const float*)d_in[7];
  const float* bv = (const float*)d_in[8];
  const float* Wo = (const float*)d_in[9];
  const float* bo = (const float*)d_in[10];

  if (ws_size < (size_t)(66u<<20)) return;

  char* ws = (char*)d_ws;
  u16* Xb = (u16*)(ws);                          // 16 MiB: bf16 input (reused x3), then ctx
  u16* Wb = (u16*)(ws + (16u<<20));              //  2 MiB: bf16 weight (reused x4)
  u16* Qb = (u16*)(ws + (18u<<20));              // 16 MiB: Q (B,H,S,dk), pre-scaled
  u16* Kb = (u16*)(ws + (34u<<20));              // 16 MiB: K (B,H,S,dk)
  u16* Vb = (u16*)(ws + (50u<<20));              // 16 MiB: V^T (B,H,dk,S)
  u16* ctx = Xb;

  const int nX8 = (M_ROWS*D_M)/8, nW8 = (D_M*D_M)/8;
  dim3 gg(M_ROWS/128, D_M/128);

  cvt_bf16<<<2048,256,0,stream>>>(query, Xb, nX8);
  cvt_bf16<<<512, 256,0,stream>>>(Wq,    Wb, nW8);
  gemm_bt<0><<<gg,256,0,stream>>>(Xb, Wb, bq, Qb, QSCALE);

  cvt_bf16<<<2048,256,0,stream>>>(key,   Xb, nX8);
  cvt_bf16<<<512, 256,0,stream>>>(Wk,    Wb, nW8);
  gemm_bt<0><<<gg,256,0,stream>>>(Xb, Wb, bk, Kb, 1.0f);

  cvt_bf16<<<2048,256,0,stream>>>(value, Xb, nX8);
  cvt_bf16<<<512, 256,0,stream>>>(Wv,    Wb, nW8);
  gemm_bt<1><<<gg,256,0,stream>>>(Xb, Wb, bv, Vb, 1.0f);

  attn_prefix<<<dim3(N_H*N_B, P_LEN/128),256,0,stream>>>(Qb, Kb, Vb, ctx);
  attn_cand  <<<dim3(N_H*N_B, (S_LEN-P_LEN)/128),256,0,stream>>>(Qb, Kb, Vb, ctx);

  cvt_bf16<<<512,256,0,stream>>>(Wo, Wb, nW8);
  gemm_bt<2><<<gg,256,0,stream>>>(ctx, Wb, bo, (float*)d_out, 1.0f);
}

// Round 5
// 267.313 us; speedup vs baseline: 1.8924x; 1.2483x over previous
//
#include <hip/hip_runtime.h>
#include <hip/hip_bf16.h>
#include <stdint.h>
#include <stddef.h>

#define D_M   1024
#define N_H   16
#define D_K   64
#define S_LEN 2048
#define N_B   4
#define P_LEN 1792
#define M_ROWS (N_B*S_LEN)   // 8192

// 0.125 * log2(e): folds 1/sqrt(dk) and the exp->exp2 conversion into Q
#define QSCALE 0.1803368801111601f

typedef unsigned short u16;
typedef __bf16  bf16x8 __attribute__((ext_vector_type(8)));
typedef __bf16  bf16x4 __attribute__((ext_vector_type(4)));
typedef __bf16  bf16x2 __attribute__((ext_vector_type(2)));
typedef float   f32x4  __attribute__((ext_vector_type(4)));
typedef float   f32x16 __attribute__((ext_vector_type(16)));
typedef unsigned u32x4 __attribute__((ext_vector_type(4)));

#define MFMA32(a,b,c)   __builtin_amdgcn_mfma_f32_16x16x32_bf16((a),(b),(c),0,0,0)
#define MFMA3216(a,b,c) __builtin_amdgcn_mfma_f32_32x32x16_bf16((a),(b),(c),0,0,0)

__device__ __forceinline__ float ex2(float x){
#if defined(__HIP_DEVICE_COMPILE__) && __has_builtin(__builtin_amdgcn_exp2f)
  return __builtin_amdgcn_exp2f(x);
#else
  return exp2f(x);
#endif
}

#define GLDS16(gp, lp) __builtin_amdgcn_global_load_lds( \
    (__attribute__((address_space(1))) void*)(gp), \
    (__attribute__((address_space(3))) void*)(lp), 16, 0, 0)

__device__ __forceinline__ u16 f2bf(float f){
  unsigned u = __builtin_bit_cast(unsigned, f);
  u += 0x7FFFu + ((u>>16)&1u);     // RNE round to bf16
  return (u16)(u>>16);
}

__device__ __forceinline__ unsigned pkbf(float a, float b){
  bf16x2 t; t[0] = (__bf16)a; t[1] = (__bf16)b;
  return __builtin_bit_cast(unsigned, t);   // compiler emits v_cvt_pk_bf16_f32
}

// v_permlane32_swap_b32: x = [x_lo | y_lo_old], y = [x_hi_old | y_hi]. (gfx950)
__device__ __forceinline__ void plswap(unsigned &x, unsigned &y){
  asm("v_permlane32_swap_b32 %0, %1" : "+v"(x), "+v"(y));
}

// ---------------- fp32 -> bf16 convert (vectorized, 8 elems/thread/iter) ----
__global__ void cvt_bf16(const float* __restrict__ in, u16* __restrict__ out, int n8){
  typedef u16 u16x8 __attribute__((ext_vector_type(8)));
  for (int i = blockIdx.x*blockDim.x + threadIdx.x; i < n8; i += gridDim.x*blockDim.x){
    const float4* p = (const float4*)(in + (size_t)i*8);
    float4 a = p[0], b = p[1];
    u16x8 o;
    o[0]=f2bf(a.x); o[1]=f2bf(a.y); o[2]=f2bf(a.z); o[3]=f2bf(a.w);
    o[4]=f2bf(b.x); o[5]=f2bf(b.y); o[6]=f2bf(b.z); o[7]=f2bf(b.w);
    *(u16x8*)(out + (size_t)i*8) = o;
  }
}

// ---------------- 128x128 bf16 NT GEMM (C = (A*B^T + bias)*scale), m97 ------
// MODE 0: out bf16 (B,H,S,dk) head-split       (Q / K projections)
// MODE 1: out bf16 (B,H,dk,S) head-split, transposed   (V projection)
// MODE 2: out fp32 (M,N) row-major             (output projection -> d_out)
template<int MODE>
__global__ __launch_bounds__(256,2)
void gemm_bt(const u16* __restrict__ A, const u16* __restrict__ Bm,
             const float* __restrict__ bias, void* __restrict__ Cout, float scale)
{
  constexpr int Kd = 1024, N = 1024;
  __shared__ __align__(16) u16 As[128*32];
  __shared__ __align__(16) u16 Bs[128*32];
  const int tid  = threadIdx.x;
  const int wid  = tid >> 6, lane = tid & 63;
  const int rowBase = blockIdx.x * 128, colBase = blockIdx.y * 128;

  const int srow = (wid<<4) + (lane>>2);
  const int scol = (lane&3) << 3;
  const u16* Ag0 = A  + (size_t)(rowBase + srow)*Kd + scol;
  const u16* Ag1 = Ag0 + (size_t)64*Kd;
  const u16* Bg0 = Bm + (size_t)(colBase + srow)*Kd + scol;
  const u16* Bg1 = Bg0 + (size_t)64*Kd;
  u16* AsW0 = As + (wid<<9);
  u16* AsW1 = As + 2048 + (wid<<9);
  u16* BsW0 = Bs + (wid<<9);
  u16* BsW1 = Bs + 2048 + (wid<<9);

  f32x4 acc[4][4] = {};
  const int fr = lane & 15, fk = (lane>>4) << 3;
  const int wr = (wid>>1) << 6, wc = (wid&1) << 6;

  for (int kt = 0; kt < Kd/32; ++kt){
    __syncthreads();
    const int ko = kt*32;
    GLDS16(Ag0+ko, AsW0); GLDS16(Ag1+ko, AsW1);
    GLDS16(Bg0+ko, BsW0); GLDS16(Bg1+ko, BsW1);
    __syncthreads();
    bf16x8 af[4], bf[4];
#pragma unroll
    for (int i=0;i<4;++i) af[i] = *(const bf16x8*)&As[(wr + i*16 + fr)*32 + fk];
#pragma unroll
    for (int i=0;i<4;++i) bf[i] = *(const bf16x8*)&Bs[(wc + i*16 + fr)*32 + fk];
#pragma unroll
    for (int i=0;i<4;++i)
#pragma unroll
      for (int j=0;j<4;++j)
        acc[i][j] = MFMA32(af[i], bf[j], acc[i][j]);
  }

  const int rr0 = (lane>>4) << 2;
#pragma unroll
  for (int i=0;i<4;++i){
#pragma unroll
    for (int j=0;j<4;++j){
      const int gc = colBase + wc + j*16 + fr;
      const float bb = bias[gc];
#pragma unroll
      for (int r=0;r<4;++r){
        const int gr = rowBase + wr + i*16 + rr0 + r;
        const float v = (acc[i][j][r] + bb) * scale;
        if (MODE == 2){
          ((float*)Cout)[(size_t)gr*N + gc] = v;
        } else {
          const int b = gr >> 11, s = gr & 2047;
          const int h = gc >> 6,  k = gc & 63;
          if (MODE == 0)
            ((u16*)Cout)[(((size_t)(b*N_H + h))*S_LEN + s)*D_K + k] = f2bf(v);
          else
            ((u16*)Cout)[(((size_t)(b*N_H + h))*D_K + k)*S_LEN + s] = f2bf(v);
        }
      }
    }
  }
}

// ---------------- attention (merged prefix+cand, 64-key pipelined steps) -----
// Lane: q-col = lane&31, half h = lane>>5. Swapped QK^T via 32x32x16 MFMA:
// lane holds 16 k-rows of S^T per subtile: k = ks + (r&3)+8*(r>>2)+4h.
// P^T -> PV B-frag: 8 cvt_pk + 4 permlane32_swap per subtile (T12).
// PV: A = V^T rows (d = q, q+32), B = P^T -> O^T in 2x f32x16.

__device__ __forceinline__ void kload_pair(bf16x8* kr, const u16* __restrict__ Kb,
                                           int ks, int q, int h){
  int ks2 = ks + 32; if (ks2 > S_LEN-32) ks2 = S_LEN-32;   // clamp (values unused)
  const u16* kp0 = Kb + (size_t)(ks  + q)*D_K + (h<<3);
  const u16* kp1 = Kb + (size_t)(ks2 + q)*D_K + (h<<3);
#pragma unroll
  for (int kb=0;kb<4;++kb){
    kr[kb]   = *(const bf16x8*)(kp0 + 16*kb);
    kr[4+kb] = *(const bf16x8*)(kp1 + 16*kb);
  }
}

// NS: #32-key subtiles (1 or 2). M0/M1 masks: 0 none, 1 causal (k>qg), 2 diag.
// PRE: prefetch next K pair at ksn into kr (after QK consumes current).
template<bool PRE, int NS, int M0, int M1>
__device__ __forceinline__ void attn_step(
    const u16* __restrict__ Kb, const u16* __restrict__ Vb,
    bf16x8* kr, const bf16x8* qf,
    int ks0, int ks1, int ksn,
    int qg, int h, int q,
    float& m, float& l, f32x16& o0, f32x16& o1)
{
  // ---- QK^T (swapped): two independent accumulator chains
  f32x16 s0 = {}, s1 = {};
  __builtin_amdgcn_s_setprio(1);
#pragma unroll
  for (int kb=0;kb<4;++kb){
    s0 = MFMA3216(kr[kb], qf[kb], s0);
    if (NS==2) s1 = MFMA3216(kr[4+kb], qf[kb], s1);
  }
  __builtin_amdgcn_s_setprio(0);

  // ---- issue V loads now; consumed after softmax (~250 cyc of cover)
  bf16x8 v0[4], v1[4];
  {
    const u16* vp0 = Vb + (size_t)q*S_LEN + ks0 + (h<<3);
#pragma unroll
    for (int db=0;db<2;++db){
      v0[2*db]   = *(const bf16x8*)(vp0 + (size_t)(32*db)*S_LEN);
      v0[2*db+1] = *(const bf16x8*)(vp0 + (size_t)(32*db)*S_LEN + 16);
    }
    if (NS==2){
      const u16* vp1 = Vb + (size_t)q*S_LEN + ks1 + (h<<3);
#pragma unroll
      for (int db=0;db<2;++db){
        v1[2*db]   = *(const bf16x8*)(vp1 + (size_t)(32*db)*S_LEN);
        v1[2*db+1] = *(const bf16x8*)(vp1 + (size_t)(32*db)*S_LEN + 16);
      }
    }
  }
  // ---- prefetch next K pair (hidden under softmax)
  if (PRE) kload_pair(kr, Kb, ksn, q, h);

  // ---- masks
  if (M0 != 0){
#pragma unroll
    for (int r=0;r<16;++r){
      const int krow = (r&3) + 8*(r>>2) + 4*h;
      if (M0==1){ if (ks0 + krow > qg) s0[r] = -1e30f; }
      if (M0==2){ if (krow != q)       s0[r] = -1e30f; }
    }
  }
  if (NS==2 && M1 != 0){
#pragma unroll
    for (int r=0;r<16;++r){
      const int krow = (r&3) + 8*(r>>2) + 4*h;
      if (M1==1){ if (ks1 + krow > qg) s1[r] = -1e30f; }
      if (M1==2){ if (krow != q)       s1[r] = -1e30f; }
    }
  }

  // ---- max: pairwise + depth-4 tree + one cross-half shfl
  float t[16];
#pragma unroll
  for (int r=0;r<16;++r) t[r] = (NS==2) ? fmaxf(s0[r], s1[r]) : s0[r];
#pragma unroll
  for (int w=8; w>=1; w>>=1)
#pragma unroll
    for (int r=0;r<w;++r) t[r] = fmaxf(t[r], t[r+w]);
  const float tm = fmaxf(t[0], __shfl_xor(t[0], 32, 64));

  const bool skip = __all(tm <= m);     // defer rescale when max didn't grow
  const float mn = skip ? m : fmaxf(m, tm);

  // ---- exp2 + tree sum
  float a[16];
#pragma unroll
  for (int r=0;r<16;++r){
    float p0 = ex2(s0[r] - mn); s0[r] = p0;
    float p1 = 0.f;
    if (NS==2){ p1 = ex2(s1[r] - mn); s1[r] = p1; }
    a[r] = p0 + p1;
  }
#pragma unroll
  for (int w=8; w>=1; w>>=1)
#pragma unroll
    for (int r=0;r<w;++r) a[r] += a[r+w];
  const float rs = a[0] + __shfl_xor(a[0], 32, 64);

  if (!skip){
    const float alpha = ex2(m - mn);
    m = mn;
    l = l*alpha + rs;
#pragma unroll
    for (int r=0;r<16;++r){ o0[r] *= alpha; o1[r] *= alpha; }
  } else {
    l += rs;
  }

  // ---- pack P^T into PV B-fragments (cvt_pk + permlane32_swap)
  unsigned w0[8];
#pragma unroll
  for (int i=0;i<8;++i) w0[i] = pkbf(s0[2*i], s0[2*i+1]);
  plswap(w0[0],w0[2]); plswap(w0[1],w0[3]);
  plswap(w0[4],w0[6]); plswap(w0[5],w0[7]);
  bf16x8 p00 = __builtin_bit_cast(bf16x8, (u32x4){w0[0],w0[1],w0[2],w0[3]});
  bf16x8 p01 = __builtin_bit_cast(bf16x8, (u32x4){w0[4],w0[5],w0[6],w0[7]});
  bf16x8 p10, p11;
  if (NS==2){
    unsigned w1[8];
#pragma unroll
    for (int i=0;i<8;++i) w1[i] = pkbf(s1[2*i], s1[2*i+1]);
    plswap(w1[0],w1[2]); plswap(w1[1],w1[3]);
    plswap(w1[4],w1[6]); plswap(w1[5],w1[7]);
    p10 = __builtin_bit_cast(bf16x8, (u32x4){w1[0],w1[1],w1[2],w1[3]});
    p11 = __builtin_bit_cast(bf16x8, (u32x4){w1[4],w1[5],w1[6],w1[7]});
  }

  // ---- PV: two accumulator chains
  __builtin_amdgcn_s_setprio(1);
  o0 = MFMA3216(v0[0], p00, o0);
  o1 = MFMA3216(v0[2], p00, o1);
  o0 = MFMA3216(v0[1], p01, o0);
  o1 = MFMA3216(v0[3], p01, o1);
  if (NS==2){
    o0 = MFMA3216(v1[0], p10, o0);
    o1 = MFMA3216(v1[2], p10, o1);
    o0 = MFMA3216(v1[1], p11, o0);
    o1 = MFMA3216(v1[3], p11, o1);
  }
  __builtin_amdgcn_s_setprio(0);
}

// grid: (N_H*N_B, 16). y=0,1 -> candidate qt=y (57 tiles, heaviest, first);
// y=2..15 -> prefix qt=15-y (LPT descending).
__global__ __launch_bounds__(256)
void attn_all(const u16* __restrict__ Q, const u16* __restrict__ K,
              const u16* __restrict__ Vt, u16* __restrict__ ctx)
{
  const int bh = blockIdx.x, t = blockIdx.y;
  const int wid = threadIdx.x >> 6, lane = threadIdx.x & 63;
  const int q = lane & 31, h = lane >> 5;

  int qg, npair, ksm, tail;   // tail: 0 = causal32, 1 = full+causal64, 2 = self32
  if (t < 2){
    const int ql = t*128 + wid*32;
    qg    = P_LEN + ql + q;
    npair = P_LEN/64;                 // 28 full pairs
    ksm   = P_LEN + ql;               // self tile position
    tail  = 2;
  } else {
    const int qt = 15 - t;
    const int qbase = qt*128 + wid*32;
    qg    = qbase + q;
    const int nfull = qbase >> 5;
    npair = nfull >> 1;
    ksm   = npair*64;                 // tail region start
    tail  = (nfull & 1) ? 1 : 0;
  }

  const u16* Kb = K  + (size_t)bh * S_LEN * D_K;
  const u16* Vb = Vt + (size_t)bh * D_K * S_LEN;
  const u16* Qp = Q + ((size_t)bh * S_LEN + qg) * D_K + (h<<3);
  bf16x8 qf[4];
#pragma unroll
  for (int kb=0;kb<4;++kb) qf[kb] = *(const bf16x8*)(Qp + 16*kb);
  float m = -1e30f, l = 0.f;
  f32x16 o0 = {}, o1 = {};

  bf16x8 kr[8];
  kload_pair(kr, Kb, 0, q, h);
  int ks = 0;
  for (int p=0; p<npair; ++p, ks+=64){
    const int ksn = (p+1 < npair) ? ks+64 : ksm;
    attn_step<true,2,0,0>(Kb, Vb, kr, qf, ks, ks+32, ksn, qg, h, q, m, l, o0, o1);
  }
  if (tail == 0)
    attn_step<false,1,1,0>(Kb, Vb, kr, qf, ksm, 0, 0, qg, h, q, m, l, o0, o1);
  else if (tail == 1)
    attn_step<false,2,0,1>(Kb, Vb, kr, qf, ksm, ksm+32, 0, qg, h, q, m, l, o0, o1);
  else
    attn_step<false,1,2,0>(Kb, Vb, kr, qf, ksm, 0, 0, qg, h, q, m, l, o0, o1);

  // ---- write O^T (row d = (r&3)+8*(r>>2)+4h + 32db, col q)
  const int b = bh >> 4, hd = bh & 15;
  const float inv = 1.f / l;
  u16* cp = ctx + ((size_t)b*S_LEN + qg)*D_M + hd*D_K;
#pragma unroll
  for (int rg=0; rg<4; ++rg){
    const int d0 = 8*rg + 4*h;
    bf16x4 oa, ob;
#pragma unroll
    for (int e=0;e<4;++e){ oa[e] = (__bf16)(o0[4*rg+e]*inv); ob[e] = (__bf16)(o1[4*rg+e]*inv); }
    *(bf16x4*)(cp + d0)      = oa;
    *(bf16x4*)(cp + 32 + d0) = ob;
  }
}

// ---------------- launcher ---------------------------------------------------
extern "C" void kernel_launch(void* const* d_in, const int* in_sizes, int n_in,
                              void* d_out, int out_size, void* d_ws, size_t ws_size,
                              hipStream_t stream)
{
  const float* query = (const float*)d_in[0];
  const float* key   = (const float*)d_in[1];
  const float* value = (const float*)d_in[2];
  const float* Wq = (const float*)d_in[3];
  const float* bq = (const float*)d_in[4];
  const float* Wk = (const float*)d_in[5];
  const float* bk = (const float*)d_in[6];
  const float* Wv = (const float*)d_in[7];
  const float* bv = (const float*)d_in[8];
  const float* Wo = (const float*)d_in[9];
  const float* bo = (const float*)d_in[10];

  if (ws_size < (size_t)(66u<<20)) return;

  char* ws = (char*)d_ws;
  u16* Xb = (u16*)(ws);                          // 16 MiB: bf16 input (reused x3), then ctx
  u16* Wb = (u16*)(ws + (16u<<20));              //  2 MiB: bf16 weight (reused x4)
  u16* Qb = (u16*)(ws + (18u<<20));              // 16 MiB: Q (B,H,S,dk), pre-scaled
  u16* Kb = (u16*)(ws + (34u<<20));              // 16 MiB: K (B,H,S,dk)
  u16* Vb = (u16*)(ws + (50u<<20));              // 16 MiB: V^T (B,H,dk,S)
  u16* ctx = Xb;

  const int nX8 = (M_ROWS*D_M)/8, nW8 = (D_M*D_M)/8;
  dim3 gg(M_ROWS/128, D_M/128);

  cvt_bf16<<<2048,256,0,stream>>>(query, Xb, nX8);
  cvt_bf16<<<512, 256,0,stream>>>(Wq,    Wb, nW8);
  gemm_bt<0><<<gg,256,0,stream>>>(Xb, Wb, bq, Qb, QSCALE);

  cvt_bf16<<<2048,256,0,stream>>>(key,   Xb, nX8);
  cvt_bf16<<<512, 256,0,stream>>>(Wk,    Wb, nW8);
  gemm_bt<0><<<gg,256,0,stream>>>(Xb, Wb, bk, Kb, 1.0f);

  cvt_bf16<<<2048,256,0,stream>>>(value, Xb, nX8);
  cvt_bf16<<<512, 256,0,stream>>>(Wv,    Wb, nW8);
  gemm_bt<1><<<gg,256,0,stream>>>(Xb, Wb, bv, Vb, 1.0f);

  attn_all<<<dim3(N_H*N_B, 16),256,0,stream>>>(Qb, Kb, Vb, ctx);

  cvt_bf16<<<512,256,0,stream>>>(Wo, Wb, nW8);
  gemm_bt<2><<<gg,256,0,stream>>>(ctx, Wb, bo, (float*)d_out, 1.0f);
}